// Round 7
// baseline (773.743 us; speedup 1.0000x reference)
//
#include <hip/hip_runtime.h>
#include <hip/hip_bf16.h>

// out[b][c] = kxx_mean[b] + kyy[c] - 2*kxy_mean[b][c]
// x[32768][64] f32, atoms[64][32][64] f32, out[256][64] f32.
// R7 = r6 pipeline (unchanged) + probe_loop diagnostic kernel: r6 main-loop
// body repeated x32 inside one dispatch so it exceeds the ~40us fill rows and
// becomes visible in rocprof top-5 with amortized-setup steady-state counters.

constexpr int   NODES = 128;
constexpr int   DD    = 64;
constexpr int   CC    = 64;
constexpr int   KK    = 32;
constexpr float GAMMA = 1.0f / 64.0f;
constexpr float LOG2E = 1.4426950408889634f;
constexpr float C1    = 2.0f * GAMMA * LOG2E;   // exp2-domain scale on S
constexpr float GL    = GAMMA * LOG2E;

typedef __attribute__((ext_vector_type(8)))  short short8;
typedef __attribute__((ext_vector_type(16))) float f32x16;

#define MFMA(a, b, c) __builtin_amdgcn_mfma_f32_32x32x16_bf16((a), (b), (c), 0, 0, 0)

__device__ __forceinline__ float fexp2(float x) {
    float r;
    asm("v_exp_f32 %0, %1" : "=v"(r) : "v"(x));
    return r;
}

__device__ __forceinline__ unsigned short f2bf(float f) {
    union { float f; unsigned int u; } a; a.f = f;
    unsigned int u = a.u;
    return (unsigned short)((u + 0x7FFFu + ((u >> 16) & 1u)) >> 16);  // RNE
}
__device__ __forceinline__ float bf2f(unsigned short b) {
    union { unsigned int u; float f; } a; a.u = ((unsigned int)b) << 16;
    return a.f;
}

// ---------------------------------------------------------------------------
// prep_atoms: atoms -> B-frag stream (hi/lo) + eck + kyy. (validated r2-r6)
// ---------------------------------------------------------------------------
__global__ __launch_bounds__(256) void prep_atoms(const float* __restrict__ atoms,
                                                  short8* __restrict__ bfrag,
                                                  float* __restrict__ eck,
                                                  float* __restrict__ kyy) {
    const int c = blockIdx.x, t = threadIdx.x;
    __shared__ float a[KK][DD + 1];
    __shared__ float an[KK];
    __shared__ float wred[4];

    const float* ac = atoms + (size_t)c * KK * DD;
    for (int i = t; i < KK * DD; i += 256) a[i >> 6][i & 63] = ac[i];
    __syncthreads();

    if (t < KK) {
        float s = 0.f;
#pragma unroll
        for (int d = 0; d < DD; ++d) s = fmaf(a[t][d], a[t][d], s);
        an[t] = s;
        eck[c * KK + t] = fexp2(-GL * s);
    }
    __syncthreads();

    {
        const int w = t >> 6, l = t & 63;
        const int kp = l & 31, kh = l >> 5;
        short8 hi, lo;
#pragma unroll
        for (int j = 0; j < 8; ++j) {
            const float f  = a[kp][w * 16 + kh * 8 + j];
            const unsigned short hb = f2bf(f);
            hi[j] = (short)hb;
            lo[j] = (short)f2bf(f - bf2f(hb));
        }
        const size_t idx = ((size_t)c * 8 + w * 2) * 64 + l;
        bfrag[idx]      = hi;
        bfrag[idx + 64] = lo;
    }

    {
        const int i = t >> 3, j0 = (t & 7) * 4;
        float s0 = 0, s1 = 0, s2 = 0, s3 = 0;
        for (int d = 0; d < DD; ++d) {
            const float aid = a[i][d];
            s0 = fmaf(aid, a[j0 + 0][d], s0);
            s1 = fmaf(aid, a[j0 + 1][d], s1);
            s2 = fmaf(aid, a[j0 + 2][d], s2);
            s3 = fmaf(aid, a[j0 + 3][d], s3);
        }
        const float ani = an[i];
        float s = fexp2(-GL * (ani + an[j0 + 0] - 2.f * s0))
                + fexp2(-GL * (ani + an[j0 + 1] - 2.f * s1))
                + fexp2(-GL * (ani + an[j0 + 2] - 2.f * s2))
                + fexp2(-GL * (ani + an[j0 + 3] - 2.f * s3));
#pragma unroll
        for (int off = 32; off; off >>= 1) s += __shfl_xor(s, off);
        if ((t & 63) == 0) wred[t >> 6] = s;
    }
    __syncthreads();
    if (t == 0) kyy[c] = (wred[0] + wred[1] + wred[2] + wred[3]) * (1.0f / (KK * KK));
}

// ---------------------------------------------------------------------------
// mmd_fused: IDENTICAL to round 6 (passing, absmax 2.44e-4).
// ---------------------------------------------------------------------------
__global__ __launch_bounds__(256, 4) void mmd_fused(const float* __restrict__ x,
                                                    const short8* __restrict__ bfrag,
                                                    const float* __restrict__ eck,
                                                    float* __restrict__ kxxp,
                                                    float* __restrict__ sxyw) {
    const int bid = blockIdx.x;
    const int b = bid >> 2, cq = bid & 3;
    const int t = threadIdx.x, w = t >> 6, l = t & 63;
    const int l31 = l & 31, kh = l >> 5;

    __shared__ short8 Bb[512];
    __shared__ float  part16[4][17][16];
    __shared__ float  norm_lds[NODES];
    __shared__ float  ec_lds[16][KK];

    float v[32];
    {
        const float* xr = x + ((size_t)(b * NODES + w * 32 + l31)) * DD + kh * 8;
#pragma unroll
        for (int kt = 0; kt < 4; ++kt) {
            const float4 p0 = *reinterpret_cast<const float4*>(xr + kt * 16);
            const float4 p1 = *reinterpret_cast<const float4*>(xr + kt * 16 + 4);
            v[kt*8+0]=p0.x; v[kt*8+1]=p0.y; v[kt*8+2]=p0.z; v[kt*8+3]=p0.w;
            v[kt*8+4]=p1.x; v[kt*8+5]=p1.y; v[kt*8+6]=p1.z; v[kt*8+7]=p1.w;
        }
    }
    float xn = 0.f;
#pragma unroll
    for (int i = 0; i < 32; ++i) xn = fmaf(v[i], v[i], xn);
    xn += __shfl_xor(xn, 32);
    if (l < 32) norm_lds[w * 32 + l] = xn;

    short8 A[4][2];
#pragma unroll
    for (int kt = 0; kt < 4; ++kt) {
        short8 hi, lo;
#pragma unroll
        for (int j = 0; j < 8; ++j) {
            const float f = v[kt * 8 + j];
            const unsigned short hb = f2bf(f);
            hi[j] = (short)hb;
            lo[j] = (short)f2bf(f - bf2f(hb));
        }
        A[kt][0] = hi; A[kt][1] = lo;
    }

    for (int e = t; e < 512; e += 256) {
        const int kt = e >> 7, h = (e >> 6) & 1, ll = e & 63;
        const float* p = x + ((size_t)(b * NODES + cq * 32 + (ll & 31))) * DD
                         + kt * 16 + ((ll >> 5) * 8);
        const float4 q0 = *reinterpret_cast<const float4*>(p);
        const float4 q1 = *reinterpret_cast<const float4*>(p + 4);
        const float vv[8] = {q0.x, q0.y, q0.z, q0.w, q1.x, q1.y, q1.z, q1.w};
        short8 f;
#pragma unroll
        for (int j = 0; j < 8; ++j) {
            const unsigned short hb = f2bf(vv[j]);
            f[j] = (h == 0) ? (short)hb : (short)f2bf(vv[j] - bf2f(hb));
        }
        Bb[e] = f;
    }
    for (int i = t; i < 512; i += 256) ec_lds[i >> 5][i & 31] = eck[cq * 512 + i];

    const short8* bq = bfrag + (size_t)(cq * 16) * 512;
    short8 r0 = bq[t];
    short8 r1 = bq[256 + t];

    __syncthreads();

    float cxv[16];
#pragma unroll
    for (int r = 0; r < 16; ++r) {
        const int ro = (r & 3) + 8 * (r >> 2) + 4 * kh;
        cxv[r] = -GL * norm_lds[w * 32 + ro];
    }
    const float ec0 = fexp2(-GL * norm_lds[cq * 32 + l31]);

    for (int it = 0; it <= 16; ++it) {
        short8 B[4][2];
#pragma unroll
        for (int kt = 0; kt < 4; ++kt)
#pragma unroll
            for (int h = 0; h < 2; ++h)
                B[kt][h] = Bb[(kt * 2 + h) * 64 + l];
        __syncthreads();

        if (it < 16) {
            Bb[t]       = r0;
            Bb[t + 256] = r1;
            if (it < 15) {
                r0 = bq[(it + 1) * 512 + t];
                r1 = bq[(it + 1) * 512 + 256 + t];
            }
        }
        const float ec = (it == 0) ? ec0 : ec_lds[it - 1][l31];

        f32x16 acc = {};
        acc = MFMA(A[0][0], B[0][0], acc);
        acc = MFMA(A[0][0], B[0][1], acc);
        acc = MFMA(A[0][1], B[0][0], acc);
        acc = MFMA(A[1][0], B[1][0], acc);
        acc = MFMA(A[1][0], B[1][1], acc);
        acc = MFMA(A[1][1], B[1][0], acc);
        acc = MFMA(A[2][0], B[2][0], acc);
        acc = MFMA(A[2][0], B[2][1], acc);
        acc = MFMA(A[2][1], B[2][0], acc);
        acc = MFMA(A[3][0], B[3][0], acc);
        acc = MFMA(A[3][0], B[3][1], acc);
        acc = MFMA(A[3][1], B[3][0], acc);

        float sa = 0.f, sb = 0.f;
#pragma unroll
        for (int r = 0; r < 16; r += 2) {
            sa += fexp2(fmaf(C1, acc[r],     cxv[r]));
            sb += fexp2(fmaf(C1, acc[r + 1], cxv[r + 1]));
        }
        float s = (sa + sb) * ec;
        s += __shfl_xor(s, 32);
        s += __shfl_xor(s, 16);
        if (l < 16) part16[w][it][l] = s;

        __syncthreads();
    }

    for (int ci = t >> 4; ci < 17; ci += 16) {
        const int g = t & 15;
        float s = part16[0][ci][g] + part16[1][ci][g]
                + part16[2][ci][g] + part16[3][ci][g];
        s += __shfl_xor(s, 8);
        s += __shfl_xor(s, 4);
        s += __shfl_xor(s, 2);
        s += __shfl_xor(s, 1);
        if (g == 0) {
            if (ci == 0) kxxp[b * 4 + cq] = s;
            else         sxyw[b * CC + cq * 16 + (ci - 1)] = s;
        }
    }
}

// ---------------------------------------------------------------------------
// probe_loop: DIAGNOSTIC. r6 main-loop body (16 atom-iters, same barriers,
// same LDS traffic, same MFMA+exp epilogue) repeated REP times inside one
// dispatch. Memory-carried deps (Bb, part16) prevent rep collapse. Results
// go to a ws sink; does not touch d_out. Same work every call.
// ---------------------------------------------------------------------------
template<int REP>
__global__ __launch_bounds__(256, 4) void probe_loop(const float* __restrict__ x,
                                                     const short8* __restrict__ bfrag,
                                                     const float* __restrict__ eck,
                                                     float* __restrict__ sink) {
    const int bid = blockIdx.x;
    const int b = bid >> 2, cq = bid & 3;
    const int t = threadIdx.x, w = t >> 6, l = t & 63;
    const int l31 = l & 31, kh = l >> 5;

    __shared__ short8 Bb[512];
    __shared__ float  part16[4][16][16];
    __shared__ float  norm_lds[NODES];
    __shared__ float  ec_lds[16][KK];

    // ---- setup identical in shape to mmd_fused ----
    float v[32];
    {
        const float* xr = x + ((size_t)(b * NODES + w * 32 + l31)) * DD + kh * 8;
#pragma unroll
        for (int kt = 0; kt < 4; ++kt) {
            const float4 p0 = *reinterpret_cast<const float4*>(xr + kt * 16);
            const float4 p1 = *reinterpret_cast<const float4*>(xr + kt * 16 + 4);
            v[kt*8+0]=p0.x; v[kt*8+1]=p0.y; v[kt*8+2]=p0.z; v[kt*8+3]=p0.w;
            v[kt*8+4]=p1.x; v[kt*8+5]=p1.y; v[kt*8+6]=p1.z; v[kt*8+7]=p1.w;
        }
    }
    float xn = 0.f;
#pragma unroll
    for (int i = 0; i < 32; ++i) xn = fmaf(v[i], v[i], xn);
    xn += __shfl_xor(xn, 32);
    if (l < 32) norm_lds[w * 32 + l] = xn;

    short8 A[4][2];
#pragma unroll
    for (int kt = 0; kt < 4; ++kt) {
        short8 hi, lo;
#pragma unroll
        for (int j = 0; j < 8; ++j) {
            const float f = v[kt * 8 + j];
            const unsigned short hb = f2bf(f);
            hi[j] = (short)hb;
            lo[j] = (short)f2bf(f - bf2f(hb));
        }
        A[kt][0] = hi; A[kt][1] = lo;
    }
    for (int i = t; i < 512; i += 256) ec_lds[i >> 5][i & 31] = eck[cq * 512 + i];
    __syncthreads();

    float cxv[16];
#pragma unroll
    for (int r = 0; r < 16; ++r) {
        const int ro = (r & 3) + 8 * (r >> 2) + 4 * kh;
        cxv[r] = -GL * norm_lds[w * 32 + ro];
    }

    const short8* bq = bfrag + (size_t)(cq * 16) * 512;

    // ---- REP x 16-iteration steady-state loop ----
    for (int rep = 0; rep < REP; ++rep) {
        short8 r0 = bq[t];
        short8 r1 = bq[256 + t];
        __syncthreads();
        Bb[t]       = r0;                 // stage tile 0
        Bb[t + 256] = r1;
        r0 = bq[512 + t];                 // prefetch tile 1
        r1 = bq[512 + 256 + t];
        __syncthreads();

        for (int it = 0; it < 16; ++it) {
            short8 B[4][2];
#pragma unroll
            for (int kt = 0; kt < 4; ++kt)
#pragma unroll
                for (int h = 0; h < 2; ++h)
                    B[kt][h] = Bb[(kt * 2 + h) * 64 + l];
            __syncthreads();

            if (it < 15) {
                Bb[t]       = r0;
                Bb[t + 256] = r1;
                if (it < 14) {
                    r0 = bq[(it + 2) * 512 + t];
                    r1 = bq[(it + 2) * 512 + 256 + t];
                }
            }
            const float ec = ec_lds[it][l31];

            f32x16 acc = {};
            acc = MFMA(A[0][0], B[0][0], acc);
            acc = MFMA(A[0][0], B[0][1], acc);
            acc = MFMA(A[0][1], B[0][0], acc);
            acc = MFMA(A[1][0], B[1][0], acc);
            acc = MFMA(A[1][0], B[1][1], acc);
            acc = MFMA(A[1][1], B[1][0], acc);
            acc = MFMA(A[2][0], B[2][0], acc);
            acc = MFMA(A[2][0], B[2][1], acc);
            acc = MFMA(A[2][1], B[2][0], acc);
            acc = MFMA(A[3][0], B[3][0], acc);
            acc = MFMA(A[3][0], B[3][1], acc);
            acc = MFMA(A[3][1], B[3][0], acc);

            float sa = 0.f, sb = 0.f;
#pragma unroll
            for (int r = 0; r < 16; r += 2) {
                sa += fexp2(fmaf(C1, acc[r],     cxv[r]));
                sb += fexp2(fmaf(C1, acc[r + 1], cxv[r + 1]));
            }
            float s = (sa + sb) * ec;
            s += __shfl_xor(s, 32);
            s += __shfl_xor(s, 16);
            if (l < 16) part16[w][it][l] = s;

            __syncthreads();
        }
    }

    __syncthreads();
    if (t < 64) {
        float accum = 0.f;
#pragma unroll
        for (int ww = 0; ww < 4; ++ww)
            for (int i = 0; i < 16; ++i) accum += part16[ww][i][t & 15];
        sink[bid * 64 + t] = accum;
    }
}

// ---------------------------------------------------------------------------
// combine: out[b][c] = sum(kxxp[b])/16384 + kyy[c] - sxyw[b][c]/2048
// ---------------------------------------------------------------------------
__global__ __launch_bounds__(256) void combine(const float* __restrict__ kxxp,
                                               const float* __restrict__ kyy,
                                               const float* __restrict__ sxyw,
                                               float* __restrict__ out) {
    const int idx = blockIdx.x * 256 + threadIdx.x;
    const int b = idx >> 6, c = idx & 63;
    const float kxx = (kxxp[b * 4 + 0] + kxxp[b * 4 + 1] +
                       kxxp[b * 4 + 2] + kxxp[b * 4 + 3]) * (1.0f / 16384.0f);
    out[idx] = kxx + kyy[c] - sxyw[idx] * (1.0f / 2048.0f);
}

extern "C" void kernel_launch(void* const* d_in, const int* in_sizes, int n_in,
                              void* d_out, int out_size, void* d_ws, size_t ws_size,
                              hipStream_t stream) {
    const float* x     = (const float*)d_in[0];   // [32768, 64]
    const float* atoms = (const float*)d_in[1];   // [64, 32, 64]
    float* out = (float*)d_out;                   // [256, 64]

    char* ws = (char*)d_ws;
    short8* bfrag = (short8*)ws;                          // 512 KiB
    float*  eck   = (float*)(ws + 524288);                // 8 KiB
    float*  kyy   = (float*)(ws + 532480);                // 256 B
    float*  kxxp  = (float*)(ws + 532736);                // 4 KiB
    float*  sxyw  = (float*)(ws + 536832);                // 64 KiB
    float*  sink  = (float*)(ws + (2u << 20));            // 256 KiB probe sink

    prep_atoms<<<dim3(CC),   dim3(256), 0, stream>>>(atoms, bfrag, eck, kyy);
    mmd_fused <<<dim3(1024), dim3(256), 0, stream>>>(x, bfrag, eck, kxxp, sxyw);
    combine   <<<dim3(CC),   dim3(256), 0, stream>>>(kxxp, kyy, sxyw, out);
    probe_loop<32><<<dim3(1024), dim3(256), 0, stream>>>(x, bfrag, eck, sink);
}

// Round 8
// 49.402 us; speedup vs baseline: 15.6623x; 15.6623x over previous
//
#include <hip/hip_runtime.h>
#include <hip/hip_bf16.h>

// out[b][c] = kxx_mean[b] + kyy[c] - 2*kxy_mean[b][c]
// x[32768][64] f32, atoms[64][32][64] f32, out[256][64] f32.
// R8: wave owns 2 A-rowtiles (24 MFMA per 8KB B-read), global_load_lds
// staging, double-buffer + 1 barrier/iter, norms in LDS (VGPR <= 128).

constexpr int   NODES = 128;
constexpr int   DD    = 64;
constexpr int   CC    = 64;
constexpr int   KK    = 32;
constexpr float GAMMA = 1.0f / 64.0f;
constexpr float LOG2E = 1.4426950408889634f;
constexpr float C1    = 2.0f * GAMMA * LOG2E;   // exp2-domain scale on S
constexpr float GL    = GAMMA * LOG2E;

typedef __attribute__((ext_vector_type(8)))  short short8;
typedef __attribute__((ext_vector_type(16))) float f32x16;

#define MFMA(a, b, c) __builtin_amdgcn_mfma_f32_32x32x16_bf16((a), (b), (c), 0, 0, 0)

__device__ __forceinline__ float fexp2(float x) {
    float r;
    asm("v_exp_f32 %0, %1" : "=v"(r) : "v"(x));
    return r;
}

__device__ __forceinline__ unsigned short f2bf(float f) {
    union { float f; unsigned int u; } a; a.f = f;
    unsigned int u = a.u;
    return (unsigned short)((u + 0x7FFFu + ((u >> 16) & 1u)) >> 16);  // RNE
}
__device__ __forceinline__ float bf2f(unsigned short b) {
    union { unsigned int u; float f; } a; a.u = ((unsigned int)b) << 16;
    return a.f;
}

// async global->LDS, 16B per lane; LDS dest must be wave-uniform base.
__device__ __forceinline__ void gl16(const void* g, void* l) {
    __builtin_amdgcn_global_load_lds(
        (const __attribute__((address_space(1))) char*)g,
        (__attribute__((address_space(3))) char*)l, 16, 0, 0);
}

// ---------------------------------------------------------------------------
// prep_atoms: atoms -> B-frag stream (hi/lo) + eck + kyy. (validated r2-r7)
// B entry: lane l holds col (l&31), k = kt*16+(l>>5)*8+j.
// tile c = 512 contiguous short8, internal offset (kt*2+h)*64 + l.
// ---------------------------------------------------------------------------
__global__ __launch_bounds__(256) void prep_atoms(const float* __restrict__ atoms,
                                                  short8* __restrict__ bfrag,
                                                  float* __restrict__ eck,
                                                  float* __restrict__ kyy) {
    const int c = blockIdx.x, t = threadIdx.x;
    __shared__ float a[KK][DD + 1];
    __shared__ float an[KK];
    __shared__ float wred[4];

    const float* ac = atoms + (size_t)c * KK * DD;
    for (int i = t; i < KK * DD; i += 256) a[i >> 6][i & 63] = ac[i];
    __syncthreads();

    if (t < KK) {
        float s = 0.f;
#pragma unroll
        for (int d = 0; d < DD; ++d) s = fmaf(a[t][d], a[t][d], s);
        an[t] = s;
        eck[c * KK + t] = fexp2(-GL * s);
    }
    __syncthreads();

    {   // fragment emit: wave wv handles ktile wv
        const int wv = t >> 6, l = t & 63;
        const int kp = l & 31, kh = l >> 5;
        short8 hi, lo;
#pragma unroll
        for (int j = 0; j < 8; ++j) {
            const float f  = a[kp][wv * 16 + kh * 8 + j];
            const unsigned short hb = f2bf(f);
            hi[j] = (short)hb;
            lo[j] = (short)f2bf(f - bf2f(hb));
        }
        const size_t idx = ((size_t)c * 8 + wv * 2) * 64 + l;
        bfrag[idx]      = hi;
        bfrag[idx + 64] = lo;
    }

    {   // kyy
        const int i = t >> 3, j0 = (t & 7) * 4;
        float s0 = 0, s1 = 0, s2 = 0, s3 = 0;
        for (int d = 0; d < DD; ++d) {
            const float aid = a[i][d];
            s0 = fmaf(aid, a[j0 + 0][d], s0);
            s1 = fmaf(aid, a[j0 + 1][d], s1);
            s2 = fmaf(aid, a[j0 + 2][d], s2);
            s3 = fmaf(aid, a[j0 + 3][d], s3);
        }
        const float ani = an[i];
        float s = fexp2(-GL * (ani + an[j0 + 0] - 2.f * s0))
                + fexp2(-GL * (ani + an[j0 + 1] - 2.f * s1))
                + fexp2(-GL * (ani + an[j0 + 2] - 2.f * s2))
                + fexp2(-GL * (ani + an[j0 + 3] - 2.f * s3));
#pragma unroll
        for (int off = 32; off; off >>= 1) s += __shfl_xor(s, off);
        if ((t & 63) == 0) wred[t >> 6] = s;
    }
    __syncthreads();
    if (t == 0) kyy[c] = (wred[0] + wred[1] + wred[2] + wred[3]) * (1.0f / (KK * KK));
}

// ---------------------------------------------------------------------------
// mmd_fused: grid 1024 = (b, cq), block 256 = 4 waves.
// wave w = (rh = w>>1, aq = w&1): A = rowtiles {2rh, 2rh+1} (rows rh*64..+63),
// atoms cq*16 + aq*8 + {0..7}. kxx = extra iteration vs Bx (x-rowtile cq).
// Double-buffered Bb via global_load_lds; 1 barrier/iter.
// ---------------------------------------------------------------------------
__global__ __launch_bounds__(256, 4) void mmd_fused(const float* __restrict__ x,
                                                    const short8* __restrict__ bfrag,
                                                    const float* __restrict__ eck,
                                                    float* __restrict__ kxxp,
                                                    float* __restrict__ sxyw) {
    const int bid = blockIdx.x;
    const int b = bid >> 2, cq = bid & 3;
    const int t = threadIdx.x, w = t >> 6, l = t & 63;
    const int l31 = l & 31, kh = l >> 5;
    const int rh = w >> 1, aq = w & 1;

    __shared__ short8 Bb[2][2][512];      // 32 KB: [buf][atom-eighth][tile]
    __shared__ float  part16[4][9][16];   // [wave][iter(8=kxx)][lane]
    __shared__ float  nrm[NODES];         // -GL*||x_row||^2 (pre-scaled)
    __shared__ float  ec_lds[16][KK];     // eck for this c-quarter

    // ---- A fragments for rowtiles 2rh, 2rh+1 ----
    short8 A[2][4][2];
#pragma unroll
    for (int i = 0; i < 2; ++i) {
        const int rt = 2 * rh + i;
        const float* xr = x + ((size_t)(b * NODES + rt * 32 + l31)) * DD + kh * 8;
        float v[32];
#pragma unroll
        for (int kt = 0; kt < 4; ++kt) {
            const float4 p0 = *reinterpret_cast<const float4*>(xr + kt * 16);
            const float4 p1 = *reinterpret_cast<const float4*>(xr + kt * 16 + 4);
            v[kt*8+0]=p0.x; v[kt*8+1]=p0.y; v[kt*8+2]=p0.z; v[kt*8+3]=p0.w;
            v[kt*8+4]=p1.x; v[kt*8+5]=p1.y; v[kt*8+6]=p1.z; v[kt*8+7]=p1.w;
        }
        float xn = 0.f;
#pragma unroll
        for (int k = 0; k < 32; ++k) xn = fmaf(v[k], v[k], xn);
        xn += __shfl_xor(xn, 32);
        if (l < 32) nrm[rt * 32 + l] = -GL * xn;
#pragma unroll
        for (int kt = 0; kt < 4; ++kt) {
            short8 hi, lo;
#pragma unroll
            for (int j = 0; j < 8; ++j) {
                const float f = v[kt * 8 + j];
                const unsigned short hb = f2bf(f);
                hi[j] = (short)hb;
                lo[j] = (short)f2bf(f - bf2f(hb));
            }
            A[i][kt][0] = hi; A[i][kt][1] = lo;
        }
    }

    // ---- Bx (x-frags of rowtile cq) -> Bb[0][0]; ec table ----
    for (int e = t; e < 512; e += 256) {
        const int kt = e >> 7, h = (e >> 6) & 1, ll = e & 63;
        const float* p = x + ((size_t)(b * NODES + cq * 32 + (ll & 31))) * DD
                         + kt * 16 + ((ll >> 5) * 8);
        const float4 q0 = *reinterpret_cast<const float4*>(p);
        const float4 q1 = *reinterpret_cast<const float4*>(p + 4);
        const float vv[8] = {q0.x, q0.y, q0.z, q0.w, q1.x, q1.y, q1.z, q1.w};
        short8 f;
#pragma unroll
        for (int j = 0; j < 8; ++j) {
            const unsigned short hb = f2bf(vv[j]);
            f[j] = (h == 0) ? (short)hb : (short)f2bf(vv[j] - bf2f(hb));
        }
        Bb[0][0][e] = f;
    }
    for (int i2 = t; i2 < 512; i2 += 256) ec_lds[i2 >> 5][i2 & 31] = eck[cq * 512 + i2];

    // ---- stage atoms (0, 8) -> Bb[1][*] via global_load_lds ----
    const short8* bq = bfrag + (size_t)(cq * 16) * 512;
#pragma unroll
    for (int j = 0; j < 4; ++j) {
        const int c  = w * 4 + j;            // wave-uniform
        const int ts = c >> 3, ci = c & 7;
        gl16(bq + (size_t)(ts ? 8 : 0) * 512 + ci * 64 + l, &Bb[1][ts][ci * 64]);
    }

    __syncthreads();   // nrm, Bx, ec_lds, atoms(0,8) all visible

    const float ec0 = fexp2(nrm[cq * 32 + l31]);

    // ---- kxx iteration: chain on A-tile (2rh+aq) vs Bx ----
    {
        f32x16 acc = {};
        if (aq == 0) {
#pragma unroll
            for (int kt = 0; kt < 4; ++kt) {
                const short8 B0 = Bb[0][0][(kt * 2) * 64 + l];
                const short8 B1 = Bb[0][0][(kt * 2 + 1) * 64 + l];
                acc = MFMA(A[0][kt][0], B0, acc);
                acc = MFMA(A[0][kt][0], B1, acc);
                acc = MFMA(A[0][kt][1], B0, acc);
            }
        } else {
#pragma unroll
            for (int kt = 0; kt < 4; ++kt) {
                const short8 B0 = Bb[0][0][(kt * 2) * 64 + l];
                const short8 B1 = Bb[0][0][(kt * 2 + 1) * 64 + l];
                acc = MFMA(A[1][kt][0], B0, acc);
                acc = MFMA(A[1][kt][0], B1, acc);
                acc = MFMA(A[1][kt][1], B0, acc);
            }
        }
        float s = 0.f;
        const float* nb = &nrm[(2 * rh + aq) * 32 + 4 * kh];
#pragma unroll
        for (int q = 0; q < 4; ++q) {
            const float4 cn = *reinterpret_cast<const float4*>(nb + 8 * q);
            s += fexp2(fmaf(C1, acc[4 * q + 0], cn.x));
            s += fexp2(fmaf(C1, acc[4 * q + 1], cn.y));
            s += fexp2(fmaf(C1, acc[4 * q + 2], cn.z));
            s += fexp2(fmaf(C1, acc[4 * q + 3], cn.w));
        }
        s *= ec0;
        s += __shfl_xor(s, 32);
        s += __shfl_xor(s, 16);
        if (l < 16) part16[w][8][l] = s;
    }
    __syncthreads();   // Bx reads done -> Bb[0] reusable

    // ---- 8 atom iterations, double-buffered, 1 barrier each ----
    for (int it = 0; it < 8; ++it) {
        const int rbuf = (it & 1) ^ 1;
        if (it < 7) {   // stage atoms (it+1, it+9) into the vacated buffer
#pragma unroll
            for (int j = 0; j < 4; ++j) {
                const int c  = w * 4 + j;
                const int ts = c >> 3, ci = c & 7;
                gl16(bq + (size_t)(((ts ? 9 : 1) + it)) * 512 + ci * 64 + l,
                     &Bb[it & 1][ts][ci * 64]);
            }
        }
        const float ec = ec_lds[aq * 8 + it][l31];

        f32x16 accA = {}, accB = {};
#pragma unroll
        for (int kt = 0; kt < 4; ++kt) {
            const short8 B0 = Bb[rbuf][aq][(kt * 2) * 64 + l];
            const short8 B1 = Bb[rbuf][aq][(kt * 2 + 1) * 64 + l];
            accA = MFMA(A[0][kt][0], B0, accA);
            accB = MFMA(A[1][kt][0], B0, accB);
            accA = MFMA(A[0][kt][0], B1, accA);
            accB = MFMA(A[1][kt][0], B1, accB);
            accA = MFMA(A[0][kt][1], B0, accA);
            accB = MFMA(A[1][kt][1], B0, accB);
        }

        float sA = 0.f, sB = 0.f;
        const float* nbA = &nrm[(2 * rh) * 32 + 4 * kh];
#pragma unroll
        for (int q = 0; q < 4; ++q) {
            const float4 cA = *reinterpret_cast<const float4*>(nbA + 8 * q);
            const float4 cB = *reinterpret_cast<const float4*>(nbA + 32 + 8 * q);
            sA += fexp2(fmaf(C1, accA[4 * q + 0], cA.x));
            sA += fexp2(fmaf(C1, accA[4 * q + 1], cA.y));
            sA += fexp2(fmaf(C1, accA[4 * q + 2], cA.z));
            sA += fexp2(fmaf(C1, accA[4 * q + 3], cA.w));
            sB += fexp2(fmaf(C1, accB[4 * q + 0], cB.x));
            sB += fexp2(fmaf(C1, accB[4 * q + 1], cB.y));
            sB += fexp2(fmaf(C1, accB[4 * q + 2], cB.z));
            sB += fexp2(fmaf(C1, accB[4 * q + 3], cB.w));
        }
        float s = (sA + sB) * ec;
        s += __shfl_xor(s, 32);
        s += __shfl_xor(s, 16);
        if (l < 16) part16[w][it][l] = s;

        __syncthreads();   // staged tiles landed (vmcnt drained) + reads done
    }

    // ---- block reduce ----
    {
        const int o = t >> 4, g = t & 15;      // o: output slot 0..15
        const int aqo = o >> 3, ito = o & 7;
        float s = part16[aqo][ito][g] + part16[2 + aqo][ito][g];
        s += __shfl_xor(s, 8);
        s += __shfl_xor(s, 4);
        s += __shfl_xor(s, 2);
        s += __shfl_xor(s, 1);
        if (g == 0) sxyw[b * CC + cq * 16 + aqo * 8 + ito] = s;
    }
    if (t < 16) {
        float s = part16[0][8][t] + part16[1][8][t]
                + part16[2][8][t] + part16[3][8][t];
        s += __shfl_xor(s, 8);
        s += __shfl_xor(s, 4);
        s += __shfl_xor(s, 2);
        s += __shfl_xor(s, 1);
        if (t == 0) kxxp[b * 4 + cq] = s;
    }
}

// ---------------------------------------------------------------------------
// combine: out[b][c] = sum(kxxp[b])/16384 + kyy[c] - sxyw[b][c]/2048
// ---------------------------------------------------------------------------
__global__ __launch_bounds__(256) void combine(const float* __restrict__ kxxp,
                                               const float* __restrict__ kyy,
                                               const float* __restrict__ sxyw,
                                               float* __restrict__ out) {
    const int idx = blockIdx.x * 256 + threadIdx.x;
    const int b = idx >> 6, c = idx & 63;
    const float kxx = (kxxp[b * 4 + 0] + kxxp[b * 4 + 1] +
                       kxxp[b * 4 + 2] + kxxp[b * 4 + 3]) * (1.0f / 16384.0f);
    out[idx] = kxx + kyy[c] - sxyw[idx] * (1.0f / 2048.0f);
}

extern "C" void kernel_launch(void* const* d_in, const int* in_sizes, int n_in,
                              void* d_out, int out_size, void* d_ws, size_t ws_size,
                              hipStream_t stream) {
    const float* x     = (const float*)d_in[0];   // [32768, 64]
    const float* atoms = (const float*)d_in[1];   // [64, 32, 64]
    float* out = (float*)d_out;                   // [256, 64]

    char* ws = (char*)d_ws;
    short8* bfrag = (short8*)ws;                          // 512 KiB
    float*  eck   = (float*)(ws + 524288);                // 8 KiB
    float*  kyy   = (float*)(ws + 532480);                // 256 B
    float*  kxxp  = (float*)(ws + 532736);                // 4 KiB
    float*  sxyw  = (float*)(ws + 536832);                // 64 KiB

    prep_atoms<<<dim3(CC),   dim3(256), 0, stream>>>(atoms, bfrag, eck, kyy);
    mmd_fused <<<dim3(1024), dim3(256), 0, stream>>>(x, bfrag, eck, kxxp, sxyw);
    combine   <<<dim3(CC),   dim3(256), 0, stream>>>(kxxp, kyy, sxyw, out);
}

// Round 9
// 32.729 us; speedup vs baseline: 23.6411x; 1.5094x over previous
//
#include <hip/hip_runtime.h>
#include <hip/hip_bf16.h>

// out[b][c] = kxx_mean[b] + kyy[c] - 2*kxy_mean[b][c]
// x[32768][64] f32, atoms[64][32][64] f32, out[256][64] f32.
// R9: SINGLE-PASS bf16 MFMA (error analysis: reference-side absmax dominates),
// prep_x emits A-frags+exact norms coalesced, gl16 B staging, 1 barrier/iter.

constexpr int   NODES = 128;
constexpr int   DD    = 64;
constexpr int   CC    = 64;
constexpr int   KK    = 32;
constexpr float GAMMA = 1.0f / 64.0f;
constexpr float LOG2E = 1.4426950408889634f;
constexpr float C1    = 2.0f * GAMMA * LOG2E;   // exp2-domain scale on S
constexpr float GL    = GAMMA * LOG2E;

typedef __attribute__((ext_vector_type(8)))  short short8;
typedef __attribute__((ext_vector_type(16))) float f32x16;

#define MFMA(a, b, c) __builtin_amdgcn_mfma_f32_32x32x16_bf16((a), (b), (c), 0, 0, 0)

__device__ __forceinline__ float fexp2(float x) {
    float r;
    asm("v_exp_f32 %0, %1" : "=v"(r) : "v"(x));
    return r;
}

__device__ __forceinline__ unsigned short f2bf(float f) {
    union { float f; unsigned int u; } a; a.f = f;
    unsigned int u = a.u;
    return (unsigned short)((u + 0x7FFFu + ((u >> 16) & 1u)) >> 16);  // RNE
}

// async global->LDS, 16B/lane; LDS dest wave-uniform base + lane*16.
__device__ __forceinline__ void gl16(const void* g, void* l) {
    __builtin_amdgcn_global_load_lds(
        (const __attribute__((address_space(1))) char*)g,
        (__attribute__((address_space(3))) char*)l, 16, 0, 0);
}

// 16-exp epilogue: sum exp2(C1*acc[r] + cx[r]) with static indices (no scratch).
__device__ __forceinline__ float epi16(const f32x16 acc, const f32x16 cx) {
    float sa = 0.f, sb = 0.f;
#pragma unroll
    for (int r = 0; r < 16; r += 2) {
        sa += fexp2(fmaf(C1, acc[r],     cx[r]));
        sb += fexp2(fmaf(C1, acc[r + 1], cx[r + 1]));
    }
    return sa + sb;
}

// ---------------------------------------------------------------------------
// prep_x: grid 256 (graph). Coalesced x load -> LDS -> A-frags (bf16 hi only)
// + exact row norms (pre-scaled by -GL). Frag entry (validated r2-r8 layout):
// lane l holds row (l&31), k = kt*16+(l>>5)*8+j. xfrag[b*1024 + (rt*4+kt)*64 + l].
// ---------------------------------------------------------------------------
__global__ __launch_bounds__(256) void prep_x(const float* __restrict__ x,
                                              short8* __restrict__ xfrag,
                                              float* __restrict__ nrm) {
    const int b = blockIdx.x, t = threadIdx.x;
    __shared__ float a[NODES][DD + 1];    // 33.3 KB, +1 pad: conflict-free

    const float4* xg = reinterpret_cast<const float4*>(x + (size_t)b * NODES * DD);
    for (int i = t; i < NODES * DD / 4; i += 256) {
        const float4 v = xg[i];
        const int r = i >> 4, c4 = (i & 15) * 4;
        a[r][c4 + 0] = v.x; a[r][c4 + 1] = v.y;
        a[r][c4 + 2] = v.z; a[r][c4 + 3] = v.w;
    }
    __syncthreads();

    if (t < NODES) {
        float s = 0.f;
#pragma unroll
        for (int d = 0; d < DD; ++d) s = fmaf(a[t][d], a[t][d], s);
        nrm[b * NODES + t] = -GL * s;
    }

#pragma unroll
    for (int j = 0; j < 4; ++j) {
        const int e = t + 256 * j;            // (rt*4+kt)*64 + l
        const int l = e & 63, sl = e >> 6;
        const int row = (sl >> 2) * 32 + (l & 31);
        const int k0  = (sl & 3) * 16 + (l >> 5) * 8;
        short8 h;
#pragma unroll
        for (int q = 0; q < 8; ++q) h[q] = (short)f2bf(a[row][k0 + q]);
        xfrag[(size_t)b * 1024 + e] = h;
    }
}

// ---------------------------------------------------------------------------
// prep_atoms: B-frags (bf16 hi only) + eck + kyy. B entry: lane l holds col
// (l&31), k = kt*16+(l>>5)*8+j. bfrag[(c*4+kt)*64 + l].
// ---------------------------------------------------------------------------
__global__ __launch_bounds__(256) void prep_atoms(const float* __restrict__ atoms,
                                                  short8* __restrict__ bfrag,
                                                  float* __restrict__ eck,
                                                  float* __restrict__ kyy) {
    const int c = blockIdx.x, t = threadIdx.x;
    __shared__ float a[KK][DD + 1];
    __shared__ float an[KK];
    __shared__ float wred[4];

    const float* ac = atoms + (size_t)c * KK * DD;
    for (int i = t; i < KK * DD; i += 256) a[i >> 6][i & 63] = ac[i];
    __syncthreads();

    if (t < KK) {
        float s = 0.f;
#pragma unroll
        for (int d = 0; d < DD; ++d) s = fmaf(a[t][d], a[t][d], s);
        an[t] = s;
        eck[c * KK + t] = fexp2(-GL * s);
    }
    __syncthreads();

    {   // fragment emit: wave wv = ktile wv
        const int wv = t >> 6, l = t & 63;
        const int kp = l & 31, khh = l >> 5;
        short8 h;
#pragma unroll
        for (int j = 0; j < 8; ++j) h[j] = (short)f2bf(a[kp][wv * 16 + khh * 8 + j]);
        bfrag[((size_t)c * 4 + wv) * 64 + l] = h;
    }

    {   // kyy (exact f32)
        const int i = t >> 3, j0 = (t & 7) * 4;
        float s0 = 0, s1 = 0, s2 = 0, s3 = 0;
        for (int d = 0; d < DD; ++d) {
            const float aid = a[i][d];
            s0 = fmaf(aid, a[j0 + 0][d], s0);
            s1 = fmaf(aid, a[j0 + 1][d], s1);
            s2 = fmaf(aid, a[j0 + 2][d], s2);
            s3 = fmaf(aid, a[j0 + 3][d], s3);
        }
        const float ani = an[i];
        float s = fexp2(-GL * (ani + an[j0 + 0] - 2.f * s0))
                + fexp2(-GL * (ani + an[j0 + 1] - 2.f * s1))
                + fexp2(-GL * (ani + an[j0 + 2] - 2.f * s2))
                + fexp2(-GL * (ani + an[j0 + 3] - 2.f * s3));
#pragma unroll
        for (int off = 32; off; off >>= 1) s += __shfl_xor(s, off);
        if ((t & 63) == 0) wred[t >> 6] = s;
    }
    __syncthreads();
    if (t == 0) kyy[c] = (wred[0] + wred[1] + wred[2] + wred[3]) * (1.0f / (KK * KK));
}

// ---------------------------------------------------------------------------
// mmd_fused: grid 1024 = (b, cq), block 256 = 4 waves, wave = (rh=w>>1, aq=w&1).
// A = rowtiles {2rh, 2rh+1} in regs; per iter one 4KB B tile feeds 8 MFMA.
// it0 = kxx (B = x-frags of rowtile cq, staged like an atom); it1..8 = atoms
// cq*16 + aq*8 + (it-1). gl16 double-buffer, 1 barrier/iter.
// ---------------------------------------------------------------------------
__global__ __launch_bounds__(256, 4) void mmd_fused(const short8* __restrict__ xfrag,
                                                    const short8* __restrict__ bfrag,
                                                    const float* __restrict__ nrm,
                                                    const float* __restrict__ eck,
                                                    float* __restrict__ kxxp,
                                                    float* __restrict__ sxyw) {
    const int bid = blockIdx.x, b = bid >> 2, cq = bid & 3;
    const int t = threadIdx.x, w = t >> 6, l = t & 63;
    const int l31 = l & 31, kh = l >> 5, rh = w >> 1, aq = w & 1;

    __shared__ short8 Bb[2][2][256];      // 16 KB: [buf][stream][kt*64+l]
    __shared__ short8 Bx[256];            // 4 KB: kxx tile
    __shared__ float  part16[4][9][16];   // 2.25 KB

    // A fragments (8 coalesced 16B loads)
    const short8* xa = xfrag + (size_t)b * 1024;
    short8 A0[4], A1[4];
#pragma unroll
    for (int kt = 0; kt < 4; ++kt) {
        A0[kt] = xa[((2 * rh) * 4 + kt) * 64 + l];
        A1[kt] = xa[((2 * rh + 1) * 4 + kt) * 64 + l];
    }

    // per-row exponent constants (already -GL*||x||^2)
    f32x16 cx0, cx1;
    {
        const float* nb = nrm + b * NODES + (2 * rh) * 32 + 4 * kh;
#pragma unroll
        for (int q = 0; q < 4; ++q) {
            const float4 v0 = *reinterpret_cast<const float4*>(nb + 8 * q);
            const float4 v1 = *reinterpret_cast<const float4*>(nb + 32 + 8 * q);
            cx0[4*q+0] = v0.x; cx0[4*q+1] = v0.y; cx0[4*q+2] = v0.z; cx0[4*q+3] = v0.w;
            cx1[4*q+0] = v1.x; cx1[4*q+1] = v1.y; cx1[4*q+2] = v1.z; cx1[4*q+3] = v1.w;
        }
    }
    const float ec0 = fexp2(nrm[b * NODES + cq * 32 + l31]);

    // prologue: stage kxx tile (wave w stages slice w)
    gl16(xa + ((size_t)cq * 4 + w) * 64 + l, &Bx[w * 64]);
    __syncthreads();

    const short8* bq = bfrag + (size_t)(cq * 16) * 4 * 64;
    const int tsw = rh, si0 = aq * 2;     // this wave's staging slices

    // ---- it0: kxx ----
    {
        // stage atom pair #0 -> buf1
        const short8* src = bq + ((size_t)(tsw * 8 + 0) * 4) * 64;
        gl16(src + (si0    ) * 64 + l, &Bb[1][tsw][(si0    ) * 64]);
        gl16(src + (si0 + 1) * 64 + l, &Bb[1][tsw][(si0 + 1) * 64]);

        short8 Bt[4];
#pragma unroll
        for (int kt = 0; kt < 4; ++kt) Bt[kt] = Bx[kt * 64 + l];
        f32x16 acc = {};
        if (aq == 0) {
#pragma unroll
            for (int kt = 0; kt < 4; ++kt) acc = MFMA(A0[kt], Bt[kt], acc);
        } else {
#pragma unroll
            for (int kt = 0; kt < 4; ++kt) acc = MFMA(A1[kt], Bt[kt], acc);
        }
        float s = epi16(acc, aq ? cx1 : cx0) * ec0;
        s += __shfl_xor(s, 32);
        s += __shfl_xor(s, 16);
        if (l < 16) part16[w][8][l] = s;
        __syncthreads();
    }

    // ---- it1..8: atoms ----
    for (int it = 1; it <= 8; ++it) {
        if (it < 8) {   // stage atom pair #it into the other buffer
            const short8* src = bq + ((size_t)(tsw * 8 + it) * 4) * 64;
            gl16(src + (si0    ) * 64 + l, &Bb[(it + 1) & 1][tsw][(si0    ) * 64]);
            gl16(src + (si0 + 1) * 64 + l, &Bb[(it + 1) & 1][tsw][(si0 + 1) * 64]);
        }
        short8 Bt[4];
#pragma unroll
        for (int kt = 0; kt < 4; ++kt) Bt[kt] = Bb[it & 1][aq][kt * 64 + l];

        f32x16 a0 = {}, a1 = {};
#pragma unroll
        for (int kt = 0; kt < 4; ++kt) {
            a0 = MFMA(A0[kt], Bt[kt], a0);
            a1 = MFMA(A1[kt], Bt[kt], a1);
        }
        const float ec = eck[(cq * 16 + aq * 8 + it - 1) * KK + l31];
        float s = (epi16(a0, cx0) + epi16(a1, cx1)) * ec;
        s += __shfl_xor(s, 32);
        s += __shfl_xor(s, 16);
        if (l < 16) part16[w][it - 1][l] = s;
        __syncthreads();
    }

    // ---- tail reduce ----
    {
        const int o = t >> 4, g = t & 15;
        const int aqo = o >> 3, ito = o & 7;
        float s = part16[aqo][ito][g] + part16[2 + aqo][ito][g];
        s += __shfl_xor(s, 8);
        s += __shfl_xor(s, 4);
        s += __shfl_xor(s, 2);
        s += __shfl_xor(s, 1);
        if (g == 0) sxyw[b * CC + cq * 16 + aqo * 8 + ito] = s;
    }
    if (t < 16) {
        float s = part16[0][8][t] + part16[1][8][t]
                + part16[2][8][t] + part16[3][8][t];
        s += __shfl_xor(s, 8);
        s += __shfl_xor(s, 4);
        s += __shfl_xor(s, 2);
        s += __shfl_xor(s, 1);
        if (t == 0) kxxp[b * 4 + cq] = s;
    }
}

// ---------------------------------------------------------------------------
// combine: out[b][c] = sum(kxxp[b])/16384 + kyy[c] - sxyw[b][c]/2048
// ---------------------------------------------------------------------------
__global__ __launch_bounds__(256) void combine(const float* __restrict__ kxxp,
                                               const float* __restrict__ kyy,
                                               const float* __restrict__ sxyw,
                                               float* __restrict__ out) {
    const int idx = blockIdx.x * 256 + threadIdx.x;
    const int b = idx >> 6, c = idx & 63;
    const float kxx = (kxxp[b * 4 + 0] + kxxp[b * 4 + 1] +
                       kxxp[b * 4 + 2] + kxxp[b * 4 + 3]) * (1.0f / 16384.0f);
    out[idx] = kxx + kyy[c] - sxyw[idx] * (1.0f / 2048.0f);
}

extern "C" void kernel_launch(void* const* d_in, const int* in_sizes, int n_in,
                              void* d_out, int out_size, void* d_ws, size_t ws_size,
                              hipStream_t stream) {
    const float* x     = (const float*)d_in[0];   // [32768, 64]
    const float* atoms = (const float*)d_in[1];   // [64, 32, 64]
    float* out = (float*)d_out;                   // [256, 64]

    char* ws = (char*)d_ws;
    short8* xfrag = (short8*)(ws);                        // 4 MiB
    short8* bfrag = (short8*)(ws + 4194304);              // 256 KiB
    float*  nrm   = (float*) (ws + 4456448);              // 128 KiB
    float*  eck   = (float*) (ws + 4587520);              // 8 KiB
    float*  kyy   = (float*) (ws + 4595712);              // 256 B
    float*  kxxp  = (float*) (ws + 4595968);              // 4 KiB
    float*  sxyw  = (float*) (ws + 4600064);              // 64 KiB

    prep_x    <<<dim3(256),  dim3(256), 0, stream>>>(x, xfrag, nrm);
    prep_atoms<<<dim3(CC),   dim3(256), 0, stream>>>(atoms, bfrag, eck, kyy);
    mmd_fused <<<dim3(1024), dim3(256), 0, stream>>>(xfrag, bfrag, nrm, eck, kxxp, sxyw);
    combine   <<<dim3(CC),   dim3(256), 0, stream>>>(kxxp, kyy, sxyw, out);
}

// Round 10
// 29.522 us; speedup vs baseline: 26.2092x; 1.1086x over previous
//
#include <hip/hip_runtime.h>
#include <hip/hip_bf16.h>

// out[b][c] = kxx_mean[b] + kyy[c] - 2*kxy_mean[b][c]
// x[32768][64] f32, atoms[64][32][64] f32, out[256][64] f32.
// R10: single-pass bf16 MFMA (validated r9). 2 atoms/iter (5 iters, half the
// barriers), cx constants in LDS (VGPR ~110 -> 4 waves/SIMD), ec preloaded,
// prep kernels merged (3 dispatches total).

constexpr int   NODES = 128;
constexpr int   DD    = 64;
constexpr int   CC    = 64;
constexpr int   KK    = 32;
constexpr float GAMMA = 1.0f / 64.0f;
constexpr float LOG2E = 1.4426950408889634f;
constexpr float C1    = 2.0f * GAMMA * LOG2E;   // exp2-domain scale on S
constexpr float GL    = GAMMA * LOG2E;

typedef __attribute__((ext_vector_type(8)))  short short8;
typedef __attribute__((ext_vector_type(16))) float f32x16;

#define MFMA(a, b, c) __builtin_amdgcn_mfma_f32_32x32x16_bf16((a), (b), (c), 0, 0, 0)

__device__ __forceinline__ float fexp2(float x) {
    float r;
    asm("v_exp_f32 %0, %1" : "=v"(r) : "v"(x));
    return r;
}

__device__ __forceinline__ unsigned short f2bf(float f) {
    union { float f; unsigned int u; } a; a.f = f;
    unsigned int u = a.u;
    return (unsigned short)((u + 0x7FFFu + ((u >> 16) & 1u)) >> 16);  // RNE
}

// async global->LDS, 16B/lane; LDS dest wave-uniform base + lane*16.
__device__ __forceinline__ void gl16(const void* g, void* l) {
    __builtin_amdgcn_global_load_lds(
        (const __attribute__((address_space(1))) char*)g,
        (__attribute__((address_space(3))) char*)l, 16, 0, 0);
}

// ---------------------------------------------------------------------------
// prep: blocks 0..255 -> per-graph A-frags + norms; 256..319 -> per-atom
// B-frags + eck + kyy. Shared LDS union (33.3 KB).
// Frag layouts (validated r2-r9): A lane l holds row (l&31), k=kt*16+(l>>5)*8+j,
// xfrag[b*1024 + (rt*4+kt)*64 + l]; B lane l holds col (l&31), same k,
// bfrag[c*256 + kt*64 + l].
// ---------------------------------------------------------------------------
__global__ __launch_bounds__(256) void prep(const float* __restrict__ x,
                                            const float* __restrict__ atoms,
                                            short8* __restrict__ xfrag,
                                            float* __restrict__ nrm,
                                            short8* __restrict__ bfrag,
                                            float* __restrict__ eck,
                                            float* __restrict__ kyy) {
    __shared__ float smem[NODES * (DD + 1)];   // 33280 B union
    const int bid = blockIdx.x, t = threadIdx.x;

    if (bid < 256) {   // ---- prep_x for graph b = bid ----
        const int b = bid;
        float (*a)[DD + 1] = (float(*)[DD + 1])smem;

        const float4* xg = reinterpret_cast<const float4*>(x + (size_t)b * NODES * DD);
        for (int i = t; i < NODES * DD / 4; i += 256) {
            const float4 v = xg[i];
            const int r = i >> 4, c4 = (i & 15) * 4;
            a[r][c4 + 0] = v.x; a[r][c4 + 1] = v.y;
            a[r][c4 + 2] = v.z; a[r][c4 + 3] = v.w;
        }
        __syncthreads();

        if (t < NODES) {
            float s = 0.f;
#pragma unroll
            for (int d = 0; d < DD; ++d) s = fmaf(a[t][d], a[t][d], s);
            nrm[b * NODES + t] = -GL * s;
        }
#pragma unroll
        for (int j = 0; j < 4; ++j) {
            const int e = t + 256 * j;            // (rt*4+kt)*64 + l
            const int l = e & 63, sl = e >> 6;
            const int row = (sl >> 2) * 32 + (l & 31);
            const int k0  = (sl & 3) * 16 + (l >> 5) * 8;
            short8 h;
#pragma unroll
            for (int q = 0; q < 8; ++q) h[q] = (short)f2bf(a[row][k0 + q]);
            xfrag[(size_t)b * 1024 + e] = h;
        }
    } else {           // ---- prep_atoms for atom c = bid - 256 ----
        const int c = bid - 256;
        float (*a)[DD + 1] = (float(*)[DD + 1])smem;        // uses [32][65]
        float* an   = smem + KK * (DD + 1);                 // 32 floats
        float* wred = an + KK;                              // 4 floats

        const float* ac = atoms + (size_t)c * KK * DD;
        for (int i = t; i < KK * DD; i += 256) a[i >> 6][i & 63] = ac[i];
        __syncthreads();

        if (t < KK) {
            float s = 0.f;
#pragma unroll
            for (int d = 0; d < DD; ++d) s = fmaf(a[t][d], a[t][d], s);
            an[t] = s;
            eck[c * KK + t] = fexp2(-GL * s);
        }
        __syncthreads();

        {   // fragment emit: wave wv = ktile wv
            const int wv = t >> 6, l = t & 63;
            const int kp = l & 31, khh = l >> 5;
            short8 h;
#pragma unroll
            for (int j = 0; j < 8; ++j) h[j] = (short)f2bf(a[kp][wv * 16 + khh * 8 + j]);
            bfrag[(size_t)c * 256 + wv * 64 + l] = h;
        }

        {   // kyy (exact f32)
            const int i = t >> 3, j0 = (t & 7) * 4;
            float s0 = 0, s1 = 0, s2 = 0, s3 = 0;
            for (int d = 0; d < DD; ++d) {
                const float aid = a[i][d];
                s0 = fmaf(aid, a[j0 + 0][d], s0);
                s1 = fmaf(aid, a[j0 + 1][d], s1);
                s2 = fmaf(aid, a[j0 + 2][d], s2);
                s3 = fmaf(aid, a[j0 + 3][d], s3);
            }
            const float ani = an[i];
            float s = fexp2(-GL * (ani + an[j0 + 0] - 2.f * s0))
                    + fexp2(-GL * (ani + an[j0 + 1] - 2.f * s1))
                    + fexp2(-GL * (ani + an[j0 + 2] - 2.f * s2))
                    + fexp2(-GL * (ani + an[j0 + 3] - 2.f * s3));
#pragma unroll
            for (int off = 32; off; off >>= 1) s += __shfl_xor(s, off);
            if ((t & 63) == 0) wred[t >> 6] = s;
        }
        __syncthreads();
        if (t == 0) kyy[c] = (wred[0] + wred[1] + wred[2] + wred[3]) * (1.0f / (KK * KK));
    }
}

// ---------------------------------------------------------------------------
// mmd_fused: grid 1024 = (b, cq), block 256 = 4 waves, wave = (rh=w>>1, aq=w&1).
// A = rowtiles {2rh, 2rh+1} in regs. 5 iterations: s=0 kxx (B = x-frags of
// rowtile cq), s=1..4 atom pairs {aq*8+2(s-1), +1}. Per iter: stage next set
// (4 gl16/wave), 2 sequential sub-phases of 8 MFMA + 32 exp, 1 barrier.
// cx constants read from LDS broadcast; ec preloaded in regs.
// ---------------------------------------------------------------------------
__global__ __launch_bounds__(256, 4) void mmd_fused(const short8* __restrict__ xfrag,
                                                    const short8* __restrict__ bfrag,
                                                    const float* __restrict__ nrm,
                                                    const float* __restrict__ eck,
                                                    float* __restrict__ kxxp,
                                                    float* __restrict__ sxyw) {
    const int bid = blockIdx.x, b = bid >> 2, cq = bid & 3;
    const int t = threadIdx.x, w = t >> 6, l = t & 63;
    const int l31 = l & 31, kh = l >> 5, rh = w >> 1, aq = w & 1;

    __shared__ short8 Bb[2][4][256];      // 32 KB: [buf][slot][kt*64+l]
    __shared__ short8 Bx[256];            // 4 KB kxx tile
    __shared__ float  part16[4][9][16];   // 2.25 KB
    __shared__ float  nl[NODES];          // 512 B row-norm constants (-GL*||x||^2)

    // A fragments (8 coalesced 16B loads)
    const short8* xa = xfrag + (size_t)b * 1024;
    short8 A0[4], A1[4];
#pragma unroll
    for (int kt = 0; kt < 4; ++kt) {
        A0[kt] = xa[((2 * rh) * 4 + kt) * 64 + l];
        A1[kt] = xa[((2 * rh + 1) * 4 + kt) * 64 + l];
    }

    // norms -> LDS
    if (t < NODES) nl[t] = nrm[b * NODES + t];

    // ec preload: 8 atoms of this wave's stream
    float ecv[8];
#pragma unroll
    for (int j = 0; j < 8; ++j)
        ecv[j] = eck[(cq * 16 + aq * 8 + j) * KK + l31];

    // prologue: stage kxx tile (wave w stages slice w)
    gl16(xa + ((size_t)cq * 4 + w) * 64 + l, &Bx[w * 64]);
    __syncthreads();   // Bx + nl visible

    const float ec0 = fexp2(nl[cq * 32 + l31]);
    const float* nbase = &nl[(2 * rh) * 32 + 4 * kh];
    const short8* bq = bfrag + (size_t)(cq * 16) * 256;

#pragma unroll
    for (int s = 0; s <= 4; ++s) {
        if (s < 4) {   // stage set s (4 tiles; wave w stages tile->slot w)
            const int ct = (w >> 1) * 8 + 2 * s + (w & 1);   // atom within quarter
            const short8* src = bq + (size_t)ct * 256;
#pragma unroll
            for (int q = 0; q < 4; ++q)
                gl16(src + q * 64 + l, &Bb[s & 1][w][q * 64]);
        }

        if (s == 0) {
            // ---- kxx: A-tile (2rh+aq) vs Bx ----
            short8 Bt[4];
#pragma unroll
            for (int kt = 0; kt < 4; ++kt) Bt[kt] = Bx[kt * 64 + l];
            f32x16 acc = {};
            if (aq == 0) {
#pragma unroll
                for (int kt = 0; kt < 4; ++kt) acc = MFMA(A0[kt], Bt[kt], acc);
            } else {
#pragma unroll
                for (int kt = 0; kt < 4; ++kt) acc = MFMA(A1[kt], Bt[kt], acc);
            }
            float ssum = 0.f;
            const float* nb = &nl[(2 * rh + aq) * 32 + 4 * kh];
#pragma unroll
            for (int q = 0; q < 4; ++q) {
                const float4 cn = *reinterpret_cast<const float4*>(nb + 8 * q);
                ssum += fexp2(fmaf(C1, acc[4 * q + 0], cn.x));
                ssum += fexp2(fmaf(C1, acc[4 * q + 1], cn.y));
                ssum += fexp2(fmaf(C1, acc[4 * q + 2], cn.z));
                ssum += fexp2(fmaf(C1, acc[4 * q + 3], cn.w));
            }
            ssum *= ec0;
            ssum += __shfl_xor(ssum, 32);
            ssum += __shfl_xor(ssum, 16);
            if (l < 16) part16[w][8][l] = ssum;
        } else {
            const int set = s - 1, buf = set & 1;
            // ---- two sequential atom sub-phases ----
#pragma unroll
            for (int p = 0; p < 2; ++p) {
                short8 Bt[4];
#pragma unroll
                for (int kt = 0; kt < 4; ++kt)
                    Bt[kt] = Bb[buf][aq * 2 + p][kt * 64 + l];
                f32x16 a0 = {}, a1 = {};
#pragma unroll
                for (int kt = 0; kt < 4; ++kt) {
                    a0 = MFMA(A0[kt], Bt[kt], a0);
                    a1 = MFMA(A1[kt], Bt[kt], a1);
                }
                float sA = 0.f, sB = 0.f;
#pragma unroll
                for (int q = 0; q < 4; ++q) {
                    const float4 cA = *reinterpret_cast<const float4*>(nbase + 8 * q);
                    const float4 cB = *reinterpret_cast<const float4*>(nbase + 32 + 8 * q);
                    sA += fexp2(fmaf(C1, a0[4 * q + 0], cA.x));
                    sA += fexp2(fmaf(C1, a0[4 * q + 1], cA.y));
                    sA += fexp2(fmaf(C1, a0[4 * q + 2], cA.z));
                    sA += fexp2(fmaf(C1, a0[4 * q + 3], cA.w));
                    sB += fexp2(fmaf(C1, a1[4 * q + 0], cB.x));
                    sB += fexp2(fmaf(C1, a1[4 * q + 1], cB.y));
                    sB += fexp2(fmaf(C1, a1[4 * q + 2], cB.z));
                    sB += fexp2(fmaf(C1, a1[4 * q + 3], cB.w));
                }
                float ssum = (sA + sB) * ecv[2 * set + p];
                ssum += __shfl_xor(ssum, 32);
                ssum += __shfl_xor(ssum, 16);
                if (l < 16) part16[w][2 * set + p][l] = ssum;
            }
        }
        __syncthreads();   // staged set landed (vmcnt drain) + reads done
    }

    // ---- tail reduce ----
    {
        const int o = t >> 4, g = t & 15;
        const int aqo = o >> 3, ito = o & 7;
        float s = part16[aqo][ito][g] + part16[2 + aqo][ito][g];
        s += __shfl_xor(s, 8);
        s += __shfl_xor(s, 4);
        s += __shfl_xor(s, 2);
        s += __shfl_xor(s, 1);
        if (g == 0) sxyw[b * CC + cq * 16 + aqo * 8 + ito] = s;
    }
    if (t < 16) {
        float s = part16[0][8][t] + part16[1][8][t]
                + part16[2][8][t] + part16[3][8][t];
        s += __shfl_xor(s, 8);
        s += __shfl_xor(s, 4);
        s += __shfl_xor(s, 2);
        s += __shfl_xor(s, 1);
        if (t == 0) kxxp[b * 4 + cq] = s;
    }
}

// ---------------------------------------------------------------------------
// combine: out[b][c] = sum(kxxp[b])/16384 + kyy[c] - sxyw[b][c]/2048
// ---------------------------------------------------------------------------
__global__ __launch_bounds__(256) void combine(const float* __restrict__ kxxp,
                                               const float* __restrict__ kyy,
                                               const float* __restrict__ sxyw,
                                               float* __restrict__ out) {
    const int idx = blockIdx.x * 256 + threadIdx.x;
    const int b = idx >> 6, c = idx & 63;
    const float kxx = (kxxp[b * 4 + 0] + kxxp[b * 4 + 1] +
                       kxxp[b * 4 + 2] + kxxp[b * 4 + 3]) * (1.0f / 16384.0f);
    out[idx] = kxx + kyy[c] - sxyw[idx] * (1.0f / 2048.0f);
}

extern "C" void kernel_launch(void* const* d_in, const int* in_sizes, int n_in,
                              void* d_out, int out_size, void* d_ws, size_t ws_size,
                              hipStream_t stream) {
    const float* x     = (const float*)d_in[0];   // [32768, 64]
    const float* atoms = (const float*)d_in[1];   // [64, 32, 64]
    float* out = (float*)d_out;                   // [256, 64]

    char* ws = (char*)d_ws;
    short8* xfrag = (short8*)(ws);                        // 4 MiB
    short8* bfrag = (short8*)(ws + 4194304);              // 256 KiB
    float*  nrm   = (float*) (ws + 4456448);              // 128 KiB
    float*  eck   = (float*) (ws + 4587520);              // 8 KiB
    float*  kyy   = (float*) (ws + 4595712);              // 256 B
    float*  kxxp  = (float*) (ws + 4595968);              // 4 KiB
    float*  sxyw  = (float*) (ws + 4600064);              // 64 KiB

    prep      <<<dim3(320),  dim3(256), 0, stream>>>(x, atoms, xfrag, nrm, bfrag, eck, kyy);
    mmd_fused <<<dim3(1024), dim3(256), 0, stream>>>(xfrag, bfrag, nrm, eck, kxxp, sxyw);
    combine   <<<dim3(CC),   dim3(256), 0, stream>>>(kxxp, kyy, sxyw, out);
}